// Round 9
// baseline (134.353 us; speedup 1.0000x reference)
//
#include <hip/hip_runtime.h>
#include <math.h>

#define BATCH   65536
#define N_IN    784
#define DD      10
#define NB      10
#define SD      100
#define N_OUTS  10

typedef float  f32x4  __attribute__((ext_vector_type(4)));
typedef short  bf16x8 __attribute__((ext_vector_type(8)));

// ws float offsets
#define WTF_F 0        // bf16 [25 K][8 ct][512]  frag-linear padded Wt
#define WDF_F 51200    // bf16 [4 kk][8 ct][512]  frag-linear padded Wd_eff
#define BD_F  59392    // f32 [128] bd_eff zero-padded
#define WO_F  59520    // f32 [10][112] Wo_eff
#define BL_F  60640    // f32 [10] blog
#define MK_F  60650    // f32 [100] mask

__device__ __forceinline__ short f2bf(float f) {
    unsigned u = __builtin_bit_cast(unsigned, f);
    unsigned r = u + 0x7fffu + ((u >> 16) & 1u);   // RNE
    return (short)(r >> 16);
}

__device__ __forceinline__ bf16x8 pack8cvt(f32x4 lo, f32x4 hi) {
    union { unsigned u[4]; bf16x8 v; } o;
    asm("v_cvt_pk_bf16_f32 %0, %1, %2" : "=v"(o.u[0]) : "v"(lo[0]), "v"(lo[1]));
    asm("v_cvt_pk_bf16_f32 %0, %1, %2" : "=v"(o.u[1]) : "v"(lo[2]), "v"(lo[3]));
    asm("v_cvt_pk_bf16_f32 %0, %1, %2" : "=v"(o.u[2]) : "v"(hi[0]), "v"(hi[1]));
    asm("v_cvt_pk_bf16_f32 %0, %1, %2" : "=v"(o.u[3]) : "v"(hi[2]), "v"(hi[3]));
    return o.v;
}

#define VMCNT0_BAR() do {                                        \
    asm volatile("s_waitcnt vmcnt(0)" ::: "memory");             \
    __builtin_amdgcn_s_barrier();                                \
    __builtin_amdgcn_sched_barrier(0); } while (0)

#define BAR_LGKM() do {                                          \
    asm volatile("s_waitcnt lgkmcnt(0)" ::: "memory");           \
    __builtin_amdgcn_s_barrier();                                \
    __builtin_amdgcn_sched_barrier(0); } while (0)

// ---------------- prep1: parallel exact fp32 gating + folded tables ----------------
__global__ __launch_bounds__(1024) void prep1_kernel(
                             const float* __restrict__ x,
                             const float* __restrict__ W_in,
                             const float* __restrict__ b_in,
                             const float* __restrict__ W_gate,
                             const float* __restrict__ b_gate,
                             const float* __restrict__ b_data,
                             const float* __restrict__ W_out,
                             const float* __restrict__ b_out,
                             float* __restrict__ out,
                             float* __restrict__ ws) {
    __shared__ float a0r0[SD];
    __shared__ float mask_l[SD];
    __shared__ float ao_l[NB];
    const int tid = threadIdx.x;

    if (tid < 800) {                     // acts0 row 0, 8-way k-split + shfl
        int c = tid >> 3, h = tid & 7;
        int s = c / DD, d = c % DD;
        const float* wcol = W_in + s * (N_IN * DD) + d;
        float acc = 0.f;
        int i0 = h * 98;
        #pragma unroll 14
        for (int i = i0; i < i0 + 98; ++i)
            acc += x[i] * wcol[i * DD];
        acc += __shfl_xor(acc, 1, 64);
        acc += __shfl_xor(acc, 2, 64);
        acc += __shfl_xor(acc, 4, 64);
        if (h == 0) a0r0[c] = fmaxf(acc + b_in[c], 0.f);
    }
    __syncthreads();

    if (tid < SD) {                      // gate[s][t] -> mask
        float g = b_gate[tid];
        int s = tid / DD;
        for (int d = 0; d < DD; ++d)
            g += a0r0[s * DD + d] * W_gate[tid * DD + d];
        mask_l[tid] = (g > 0.f) ? 1.f : 0.f;
    }
    __syncthreads();

    if (tid < NB) {
        float any = 0.f;
        for (int s = 0; s < NB; ++s) any = fmaxf(any, mask_l[s * DD + tid]);
        ao_l[tid] = any;
    }
    if (tid == 0) {
        float sum = 0.f;
        for (int i = 0; i < SD; ++i) sum += mask_l[i];
        out[(long)BATCH * N_OUTS] = sum / 20.0f;          // prob_open_gate
    }
    __syncthreads();

    if (tid < SD) ws[MK_F + tid] = mask_l[tid];

    for (int idx = tid; idx < 128; idx += blockDim.x) {    // bd_eff padded
        float v = 0.f;
        if (idx < SD) {
            int t = idx / DD, e = idx % DD;
            for (int s = 0; s < NB; ++s)
                v += mask_l[s * DD + t] * b_data[(s * NB + t) * DD + e];
        }
        ws[BD_F + idx] = v;
    }
    for (int idx = tid; idx < 10 * 112; idx += blockDim.x) {   // Wo_eff
        int o = idx / 112, te = idx % 112;
        float v = 0.f;
        if (te < SD) {
            int t = te / DD, e = te % DD;
            v = ao_l[t] * W_out[(t * DD + e) * N_OUTS + o];
        }
        ws[WO_F + idx] = v;
    }
    if (tid < N_OUTS) {                  // blog
        float v = 0.f;
        for (int t = 0; t < NB; ++t) v += ao_l[t] * b_out[t * N_OUTS + tid];
        ws[BL_F + tid] = v;
    }
}

// ---------------- prep2: bf16 fragment-linear weight tables (8-ct padded) ----------------
__global__ void prep2_kernel(const float* __restrict__ W_in,
                             const float* __restrict__ W_data,
                             float* __restrict__ ws) {
    short* wtf = (short*)(ws + WTF_F);
    short* wdf = (short*)(ws + WDF_F);
    const float* mask = ws + MK_F;
    const int n1 = 25 * 8 * 512;     // 102400
    const int n2 = 4 * 8 * 512;      // 16384
    for (int idx = blockIdx.x * blockDim.x + threadIdx.x; idx < n1 + n2;
         idx += gridDim.x * blockDim.x) {
        if (idx < n1) {
            int K = idx / 4096, rem = idx % 4096;
            int ct = rem / 512, l2 = rem % 512;
            int l = l2 >> 3, e = l2 & 7;
            int r = l & 15, g = l >> 4;
            int c = 16 * ct + r, k = K * 32 + g * 8 + e;
            float v = (c < SD && k < N_IN)
                          ? W_in[(c / DD) * (N_IN * DD) + k * DD + (c % DD)] : 0.f;
            wtf[idx] = f2bf(v);
        } else {
            int i2 = idx - n1;
            int kk = i2 / 4096, rem = i2 % 4096;
            int ct = rem / 512, l2 = rem % 512;
            int l = l2 >> 3, e = l2 & 7;
            int r = l & 15, g = l >> 4;
            int m = 16 * ct + r, k = kk * 32 + g * 8 + e;
            float v = 0.f;
            if (m < SD && k < SD) {
                int t = m / DD, eo = m % DD, s = k / DD, d = k % DD;
                v = mask[s * DD + t] * W_data[((s * NB + t) * DD + d) * DD + eo];
            }
            wdf[i2] = f2bf(v);
        }
    }
}

// ---------------- main: persistent blocks, linear DMA staging, reg-resident weights ----------------
// Block = 256 thr / 4 waves; wave w owns col-tiles {w, w+4} (ct 7 = zero pad).
// 8 tiles of 16 rows per block; x tile = 50176 B staged by 49 linear 1-KB DMAs.
__global__ __launch_bounds__(256, 2) void main_kernel(
        const float* __restrict__ x,
        const float* __restrict__ b_in,
        const float* __restrict__ ws,
        float* __restrict__ out) {
    __shared__ __align__(16) unsigned char ldsx[50176];   // [16 rows][3136 B] linear
    __shared__ __align__(16) short a0b[16 * 136];
    __shared__ __align__(16) float a1[16 * 132];
    __shared__ float WoL[10 * 116];
    __shared__ float blL[16];
    __shared__ float lgL[160];

    const int tid  = threadIdx.x;
    const int w    = tid >> 6;
    const int lane = tid & 63;
    const int g    = lane >> 4;
    const int r    = lane & 15;
    const size_t rowbase = (size_t)blockIdx.x * 128;
    const char* xblk = (const char*)(x + rowbase * N_IN);

    const short* wtf = (const short*)(ws + WTF_F);
    const short* wdf = (const short*)(ws + WDF_F);

    // one-time: Wo/bl -> LDS; weights -> registers; biases -> registers
    for (int idx = tid; idx < 10 * 112; idx += 256) {
        int o = idx / 112, te = idx % 112;
        WoL[o * 116 + te] = ws[WO_F + idx];
    }
    if (tid < 10) blL[tid] = ws[BL_F + tid];

    bf16x8 wt0[25], wt1[25];
    #pragma unroll
    for (int K = 0; K < 25; ++K) {
        wt0[K] = *(const bf16x8*)(wtf + (K * 8 + w) * 512 + lane * 8);
        wt1[K] = *(const bf16x8*)(wtf + (K * 8 + w + 4) * 512 + lane * 8);
    }
    float bi0[4], bi1[4], bd0[4], bd1[4];
    #pragma unroll
    for (int j = 0; j < 4; ++j) {
        int cA = 16 * w + 4 * g + j;           // 0..63, always < 100
        int cB = 16 * (w + 4) + 4 * g + j;     // 64..127
        bi0[j] = b_in[cA];
        bi1[j] = (cB < SD) ? b_in[cB] : 0.f;
        bd0[j] = ws[BD_F + cA];
        bd1[j] = ws[BD_F + cB];
    }

#define STAGE(t) do {                                                          \
    const char* _src = xblk + (size_t)(t) * 50176;                             \
    _Pragma("unroll")                                                          \
    for (int _q = 0; _q < 13; ++_q) {                                          \
        int _I = w + 4 * _q;                                                   \
        if (_I < 49) {                                                         \
            __builtin_amdgcn_global_load_lds(                                  \
                (const __attribute__((address_space(1))) unsigned int*)        \
                    (_src + _I * 1024 + lane * 16),                            \
                (__attribute__((address_space(3))) unsigned int*)              \
                    (ldsx + _I * 1024),                                        \
                16, 0, 0);                                                     \
        }                                                                      \
    }                                                                          \
} while (0)

    STAGE(0);

    for (int t = 0; t < 8; ++t) {
        VMCNT0_BAR();                         // x tile resident (and prior stores done)

        // ---- phase 2: both col-tiles over all K, weights from registers ----
        f32x4 accA = (f32x4){0.f, 0.f, 0.f, 0.f};
        f32x4 accB = (f32x4){0.f, 0.f, 0.f, 0.f};
        const unsigned char* xrow = ldsx + r * 3136;
        #pragma unroll
        for (int K = 0; K < 25; ++K) {
            int off = K * 128 + g * 32;
            if (K == 24 && g >= 2) off = g * 32;   // clamp: weights are zero for k>=784
            f32x4 lo = *(const f32x4*)(xrow + off);
            f32x4 hi = *(const f32x4*)(xrow + off + 16);
            bf16x8 bf = pack8cvt(lo, hi);
            accA = __builtin_amdgcn_mfma_f32_16x16x32_bf16(wt0[K], bf, accA, 0, 0, 0);
            accB = __builtin_amdgcn_mfma_f32_16x16x32_bf16(wt1[K], bf, accB, 0, 0, 0);
        }
        // bias + relu + cvt -> a0b (cols 112..127 are pad ct: bias 0, acc 0 -> zeros)
        {
            short* myrow = a0b + r * 136;
            int c0A = 16 * w + 4 * g, c0B = c0A + 64;
            float vA0 = fmaxf(accA[0] + bi0[0], 0.f), vA1 = fmaxf(accA[1] + bi0[1], 0.f);
            float vA2 = fmaxf(accA[2] + bi0[2], 0.f), vA3 = fmaxf(accA[3] + bi0[3], 0.f);
            float vB0 = fmaxf(accB[0] + bi1[0], 0.f), vB1 = fmaxf(accB[1] + bi1[1], 0.f);
            float vB2 = fmaxf(accB[2] + bi1[2], 0.f), vB3 = fmaxf(accB[3] + bi1[3], 0.f);
            unsigned pA01, pA23, pB01, pB23;
            asm("v_cvt_pk_bf16_f32 %0, %1, %2" : "=v"(pA01) : "v"(vA0), "v"(vA1));
            asm("v_cvt_pk_bf16_f32 %0, %1, %2" : "=v"(pA23) : "v"(vA2), "v"(vA3));
            asm("v_cvt_pk_bf16_f32 %0, %1, %2" : "=v"(pB01) : "v"(vB0), "v"(vB1));
            asm("v_cvt_pk_bf16_f32 %0, %1, %2" : "=v"(pB23) : "v"(vB2), "v"(vB3));
            *(uint2*)(myrow + c0A) = make_uint2(pA01, pA23);
            *(uint2*)(myrow + c0B) = make_uint2(pB01, pB23);
        }
        BAR_LGKM();                           // x reads retired; a0b visible

        if (t + 1 < 8) STAGE(t + 1);          // DMA overlaps 3a/3b/softmax

        // ---- phase 3a: acts1 = relu(acts0 @ Wd^T + bd), K=128 ----
        bf16x8 wdA[4], wdB[4];
        #pragma unroll
        for (int kk = 0; kk < 4; ++kk) {
            wdA[kk] = *(const bf16x8*)(wdf + (kk * 8 + w) * 512 + lane * 8);
            wdB[kk] = *(const bf16x8*)(wdf + (kk * 8 + w + 4) * 512 + lane * 8);
        }
        f32x4 a2A = (f32x4){0.f, 0.f, 0.f, 0.f};
        f32x4 a2B = (f32x4){0.f, 0.f, 0.f, 0.f};
        #pragma unroll
        for (int kk = 0; kk < 4; ++kk) {
            bf16x8 bf = *(const bf16x8*)(a0b + r * 136 + kk * 32 + g * 8);
            a2A = __builtin_amdgcn_mfma_f32_16x16x32_bf16(wdA[kk], bf, a2A, 0, 0, 0);
            a2B = __builtin_amdgcn_mfma_f32_16x16x32_bf16(wdB[kk], bf, a2B, 0, 0, 0);
        }
        {
            int c0A = 16 * w + 4 * g, c0B = c0A + 64;
            f32x4 oA, oB;
            #pragma unroll
            for (int j = 0; j < 4; ++j) {
                oA[j] = fmaxf(a2A[j] + bd0[j], 0.f);
                oB[j] = fmaxf(a2B[j] + bd1[j], 0.f);
            }
            *(f32x4*)(a1 + r * 132 + c0A) = oA;
            *(f32x4*)(a1 + r * 132 + c0B) = oB;
        }
        BAR_LGKM();

        // ---- phase 3b: logits ----
        if (tid < 160) {
            int rr = tid / 10, o = tid - rr * 10;
            float s = blL[o];
            const float* arow = a1 + rr * 132;
            const float* wo = WoL + o * 116;
            #pragma unroll
            for (int q = 0; q < 28; ++q) {
                f32x4 a = *(const f32x4*)(arow + q * 4);
                f32x4 wv = *(const f32x4*)(wo + q * 4);
                s += a[0] * wv[0] + a[1] * wv[1] + a[2] * wv[2] + a[3] * wv[3];
            }
            lgL[tid] = s;
        }
        BAR_LGKM();

        // ---- softmax + store ----
        if (tid < 160) {
            int rr = tid / 10, o = tid - rr * 10;
            float m = -1e30f;
            #pragma unroll
            for (int j = 0; j < 10; ++j) m = fmaxf(m, lgL[rr * 10 + j]);
            float ssum = 0.f;
            #pragma unroll
            for (int j = 0; j < 10; ++j) ssum += expf(lgL[rr * 10 + j] - m);
            out[(rowbase + (size_t)t * 16 + rr) * N_OUTS + o] = lgL[tid] - m - logf(ssum);
        }
        // loop top: vmcnt(0) covers both the DMA prefetch and these stores
    }
#undef STAGE
}

extern "C" void kernel_launch(void* const* d_in, const int* in_sizes, int n_in,
                              void* d_out, int out_size, void* d_ws, size_t ws_size,
                              hipStream_t stream) {
    const float* x      = (const float*)d_in[0];
    const float* W_in   = (const float*)d_in[1];
    const float* b_in   = (const float*)d_in[2];
    const float* W_gate = (const float*)d_in[3];
    const float* b_gate = (const float*)d_in[4];
    const float* W_data = (const float*)d_in[5];
    const float* b_data = (const float*)d_in[6];
    const float* W_out  = (const float*)d_in[7];
    const float* b_out  = (const float*)d_in[8];
    float* out = (float*)d_out;
    float* ws  = (float*)d_ws;

    prep1_kernel<<<1, 1024, 0, stream>>>(x, W_in, b_in, W_gate, b_gate,
                                         b_data, W_out, b_out, out, ws);
    prep2_kernel<<<256, 256, 0, stream>>>(W_in, W_data, ws);
    main_kernel<<<512, 256, 0, stream>>>(x, b_in, ws, out);
}

// Round 10
// 83.438 us; speedup vs baseline: 1.6102x; 1.6102x over previous
//
#include <hip/hip_runtime.h>
#include <math.h>

#define BATCH   65536
#define N_IN    784
#define DD      10
#define NB      10
#define SD      100
#define N_OUTS  10
#define TILES   16
#define ROWST   16

typedef float  f32x4  __attribute__((ext_vector_type(4)));
typedef short  bf16x8 __attribute__((ext_vector_type(8)));

// ws float offsets
#define WTF_F 0        // bf16 [25 K][8 ct][512]  frag-linear padded Wt      (51200 f)
#define WDF_F 51200    // bf16 [4 kk][8 ct][512]  frag-linear padded Wd_eff  (8192 f)
#define WOF_F 59392    // bf16 [4 kk][512]        frag-linear Wo_eff A-frags (1024 f)
#define BD_F  60416    // f32 [128] bd_eff zero-padded
#define WO_F  60544    // f32 [10][112] Wo_eff (source for WOF)
#define BL_F  61664    // f32 [16] blog
#define MK_F  61680    // f32 [100] mask

__device__ __forceinline__ short f2bf(float f) {
    unsigned u = __builtin_bit_cast(unsigned, f);
    unsigned r = u + 0x7fffu + ((u >> 16) & 1u);   // RNE
    return (short)(r >> 16);
}

__device__ __forceinline__ bf16x8 pack8cvt(f32x4 lo, f32x4 hi) {
    union { unsigned u[4]; bf16x8 v; } o;
    asm("v_cvt_pk_bf16_f32 %0, %1, %2" : "=v"(o.u[0]) : "v"(lo[0]), "v"(lo[1]));
    asm("v_cvt_pk_bf16_f32 %0, %1, %2" : "=v"(o.u[1]) : "v"(lo[2]), "v"(lo[3]));
    asm("v_cvt_pk_bf16_f32 %0, %1, %2" : "=v"(o.u[2]) : "v"(hi[0]), "v"(hi[1]));
    asm("v_cvt_pk_bf16_f32 %0, %1, %2" : "=v"(o.u[3]) : "v"(hi[2]), "v"(hi[3]));
    return o.v;
}

#define VMCNT0_BAR() do {                                        \
    asm volatile("s_waitcnt vmcnt(0)" ::: "memory");             \
    __builtin_amdgcn_s_barrier();                                \
    __builtin_amdgcn_sched_barrier(0); } while (0)

#define BAR_LGKM() do {                                          \
    asm volatile("s_waitcnt lgkmcnt(0)" ::: "memory");           \
    __builtin_amdgcn_s_barrier();                                \
    __builtin_amdgcn_sched_barrier(0); } while (0)

// ---------------- prep1: parallel exact fp32 gating + folded tables ----------------
__global__ __launch_bounds__(1024) void prep1_kernel(
                             const float* __restrict__ x,
                             const float* __restrict__ W_in,
                             const float* __restrict__ b_in,
                             const float* __restrict__ W_gate,
                             const float* __restrict__ b_gate,
                             const float* __restrict__ b_data,
                             const float* __restrict__ W_out,
                             const float* __restrict__ b_out,
                             float* __restrict__ out,
                             float* __restrict__ ws) {
    __shared__ float a0r0[SD];
    __shared__ float mask_l[SD];
    __shared__ float ao_l[NB];
    const int tid = threadIdx.x;

    if (tid < 800) {                     // acts0 row 0, 8-way k-split + shfl
        int c = tid >> 3, h = tid & 7;
        int s = c / DD, d = c % DD;
        const float* wcol = W_in + s * (N_IN * DD) + d;
        float acc = 0.f;
        int i0 = h * 98;
        #pragma unroll 14
        for (int i = i0; i < i0 + 98; ++i)
            acc += x[i] * wcol[i * DD];
        acc += __shfl_xor(acc, 1, 64);
        acc += __shfl_xor(acc, 2, 64);
        acc += __shfl_xor(acc, 4, 64);
        if (h == 0) a0r0[c] = fmaxf(acc + b_in[c], 0.f);
    }
    __syncthreads();

    if (tid < SD) {                      // gate[s][t] -> mask
        float g = b_gate[tid];
        int s = tid / DD;
        for (int d = 0; d < DD; ++d)
            g += a0r0[s * DD + d] * W_gate[tid * DD + d];
        mask_l[tid] = (g > 0.f) ? 1.f : 0.f;
    }
    __syncthreads();

    if (tid < NB) {
        float any = 0.f;
        for (int s = 0; s < NB; ++s) any = fmaxf(any, mask_l[s * DD + tid]);
        ao_l[tid] = any;
    }
    if (tid == 0) {
        float sum = 0.f;
        for (int i = 0; i < SD; ++i) sum += mask_l[i];
        out[(long)BATCH * N_OUTS] = sum / 20.0f;          // prob_open_gate
    }
    __syncthreads();

    if (tid < SD) ws[MK_F + tid] = mask_l[tid];

    for (int idx = tid; idx < 128; idx += blockDim.x) {    // bd_eff padded
        float v = 0.f;
        if (idx < SD) {
            int t = idx / DD, e = idx % DD;
            for (int s = 0; s < NB; ++s)
                v += mask_l[s * DD + t] * b_data[(s * NB + t) * DD + e];
        }
        ws[BD_F + idx] = v;
    }
    for (int idx = tid; idx < 10 * 112; idx += blockDim.x) {   // Wo_eff
        int o = idx / 112, te = idx % 112;
        float v = 0.f;
        if (te < SD) {
            int t = te / DD, e = te % DD;
            v = ao_l[t] * W_out[(t * DD + e) * N_OUTS + o];
        }
        ws[WO_F + idx] = v;
    }
    if (tid < N_OUTS) {                  // blog
        float v = 0.f;
        for (int t = 0; t < NB; ++t) v += ao_l[t] * b_out[t * N_OUTS + tid];
        ws[BL_F + tid] = v;
    }
}

// ---------------- prep2: bf16 fragment-linear tables (Wt, Wd, Wo) ----------------
__global__ void prep2_kernel(const float* __restrict__ W_in,
                             const float* __restrict__ W_data,
                             float* __restrict__ ws) {
    short* wtf = (short*)(ws + WTF_F);
    short* wdf = (short*)(ws + WDF_F);
    short* wof = (short*)(ws + WOF_F);
    const float* mask = ws + MK_F;
    const int n1 = 25 * 8 * 512;     // 102400
    const int n2 = 4 * 8 * 512;      // 16384
    const int n3 = 4 * 512;          // 2048
    for (int idx = blockIdx.x * blockDim.x + threadIdx.x; idx < n1 + n2 + n3;
         idx += gridDim.x * blockDim.x) {
        if (idx < n1) {
            int K = idx / 4096, rem = idx % 4096;
            int ct = rem / 512, l2 = rem % 512;
            int l = l2 >> 3, e = l2 & 7;
            int r = l & 15, g = l >> 4;
            int c = 16 * ct + r, k = K * 32 + g * 8 + e;
            float v = (c < SD && k < N_IN)
                          ? W_in[(c / DD) * (N_IN * DD) + k * DD + (c % DD)] : 0.f;
            wtf[idx] = f2bf(v);
        } else if (idx < n1 + n2) {
            int i2 = idx - n1;
            int kk = i2 / 4096, rem = i2 % 4096;
            int ct = rem / 512, l2 = rem % 512;
            int l = l2 >> 3, e = l2 & 7;
            int r = l & 15, g = l >> 4;
            int m = 16 * ct + r, k = kk * 32 + g * 8 + e;
            float v = 0.f;
            if (m < SD && k < SD) {
                int t = m / DD, eo = m % DD, s = k / DD, d = k % DD;
                v = mask[s * DD + t] * W_data[((s * NB + t) * DD + d) * DD + eo];
            }
            wdf[i2] = f2bf(v);
        } else {
            int i3 = idx - n1 - n2;
            int kk = i3 / 512, l2 = i3 % 512;
            int l = l2 >> 3, e = l2 & 7;
            int o = l & 15, g = l >> 4;
            int te = kk * 32 + g * 8 + e;
            float v = (o < 10 && te < 112) ? ws[WO_F + o * 112 + te] : 0.f;
            wof[i3] = f2bf(v);
        }
    }
}

// ---------------- main: persistent, dbuf linear DMA, all weights in registers ----------------
// 256 blocks x 512 thr (8 waves, 1 ct each). Per block: 16 tiles x 16 rows.
// LDS: ldsx[2][50176] x dbuf + a0b/a1b bf16 [16][136].
__global__ __launch_bounds__(512, 2) void main_kernel(
        const float* __restrict__ x,
        const float* __restrict__ b_in,
        const float* __restrict__ ws,
        float* __restrict__ out) {
    __shared__ __align__(16) unsigned char ldsx[2][50176];
    __shared__ __align__(16) short a0b[16 * 136];
    __shared__ __align__(16) short a1b[16 * 136];

    const int tid  = threadIdx.x;
    const int w    = tid >> 6;
    const int lane = tid & 63;
    const int g    = lane >> 4;
    const int r    = lane & 15;
    const size_t rowbase = (size_t)blockIdx.x * (TILES * ROWST);
    const char* xblk = (const char*)x + rowbase * (N_IN * 4);

    const short* wtf = (const short*)(ws + WTF_F);
    const short* wdf = (const short*)(ws + WDF_F);
    const short* wof = (const short*)(ws + WOF_F);

    // ---- one-time: weights + biases -> registers ----
    bf16x8 wt[25];
    #pragma unroll
    for (int K = 0; K < 25; ++K)
        wt[K] = *(const bf16x8*)(wtf + (K * 8 + w) * 512 + lane * 8);
    bf16x8 wd[4], wo[4];
    #pragma unroll
    for (int kk = 0; kk < 4; ++kk) {
        wd[kk] = *(const bf16x8*)(wdf + (kk * 8 + w) * 512 + lane * 8);
        wo[kk] = *(const bf16x8*)(wof + kk * 512 + lane * 8);
    }
    float bi[4], bd[4], blv[4];
    #pragma unroll
    for (int j = 0; j < 4; ++j) {
        int c = 16 * w + 4 * g + j;
        bi[j] = (c < SD) ? b_in[c] : 0.f;
        bd[j] = ws[BD_F + c];
        int o = 4 * g + j;
        blv[j] = (o < 10) ? ws[BL_F + o] : 0.f;
    }

#define STAGE(t, buf) do {                                                     \
    const char* _src = xblk + (size_t)(t) * 50176;                             \
    _Pragma("unroll")                                                          \
    for (int _q = 0; _q < 7; ++_q) {                                           \
        int _I = w + 8 * _q;                                                   \
        if (_I < 49) {                                                         \
            __builtin_amdgcn_global_load_lds(                                  \
                (const __attribute__((address_space(1))) unsigned int*)        \
                    (_src + _I * 1024 + lane * 16),                            \
                (__attribute__((address_space(3))) unsigned int*)              \
                    (&ldsx[buf][0] + _I * 1024),                               \
                16, 0, 0);                                                     \
        }                                                                      \
    }                                                                          \
} while (0)

    STAGE(0, 0);

    for (int t = 0; t < TILES; ++t) {
        const int cur = t & 1;
        VMCNT0_BAR();                         // STAGE(t) landed; old stores drained
        if (t + 1 < TILES) STAGE(t + 1, cur ^ 1);   // full-tile overlap window

        // ---- phase 2: acts0 col-tile [16w,16w+16), weights in registers ----
        f32x4 acc = (f32x4){0.f, 0.f, 0.f, 0.f};
        const unsigned char* xb = &ldsx[cur][0] + r * 3136 + g * 32;
        #pragma unroll
        for (int K = 0; K < 25; ++K) {
            const unsigned char* p = xb + K * 128;
            if (K == 24 && g >= 2) p = xb;    // k>=784: weights zero; avoid OOB/Inf
            f32x4 lo = *(const f32x4*)(p);
            f32x4 hi = *(const f32x4*)(p + 16);
            bf16x8 bf = pack8cvt(lo, hi);
            acc = __builtin_amdgcn_mfma_f32_16x16x32_bf16(wt[K], bf, acc, 0, 0, 0);
        }
        {   // bias + relu + cvt -> a0b
            short* myrow = a0b + r * 136;
            int c0 = 16 * w + 4 * g;
            float v0 = fmaxf(acc[0] + bi[0], 0.f), v1 = fmaxf(acc[1] + bi[1], 0.f);
            float v2 = fmaxf(acc[2] + bi[2], 0.f), v3 = fmaxf(acc[3] + bi[3], 0.f);
            unsigned p01, p23;
            asm("v_cvt_pk_bf16_f32 %0, %1, %2" : "=v"(p01) : "v"(v0), "v"(v1));
            asm("v_cvt_pk_bf16_f32 %0, %1, %2" : "=v"(p23) : "v"(v2), "v"(v3));
            *(uint2*)(myrow + c0) = make_uint2(p01, p23);
        }
        BAR_LGKM();

        // ---- phase 3a: acts1 = relu(acts0 @ Wd^T + bd), K=128 ----
        f32x4 acc2 = (f32x4){0.f, 0.f, 0.f, 0.f};
        #pragma unroll
        for (int kk = 0; kk < 4; ++kk) {
            bf16x8 bf = *(const bf16x8*)(a0b + r * 136 + kk * 32 + g * 8);
            acc2 = __builtin_amdgcn_mfma_f32_16x16x32_bf16(wd[kk], bf, acc2, 0, 0, 0);
        }
        {
            short* myrow = a1b + r * 136;
            int c0 = 16 * w + 4 * g;
            float v0 = fmaxf(acc2[0] + bd[0], 0.f), v1 = fmaxf(acc2[1] + bd[1], 0.f);
            float v2 = fmaxf(acc2[2] + bd[2], 0.f), v3 = fmaxf(acc2[3] + bd[3], 0.f);
            unsigned p01, p23;
            asm("v_cvt_pk_bf16_f32 %0, %1, %2" : "=v"(p01) : "v"(v0), "v"(v1));
            asm("v_cvt_pk_bf16_f32 %0, %1, %2" : "=v"(p23) : "v"(v2), "v"(v3));
            *(uint2*)(myrow + c0) = make_uint2(p01, p23);
        }
        BAR_LGKM();

        // ---- phase 3b: logits = acts1 @ Wo^T via MFMA (every wave, identical) ----
        f32x4 accL = (f32x4){0.f, 0.f, 0.f, 0.f};
        #pragma unroll
        for (int kk = 0; kk < 4; ++kk) {
            bf16x8 bf = *(const bf16x8*)(a1b + r * 136 + kk * 32 + g * 8);
            accL = __builtin_amdgcn_mfma_f32_16x16x32_bf16(wo[kk], bf, accL, 0, 0, 0);
        }
        float lgf[4];
        #pragma unroll
        for (int j = 0; j < 4; ++j)
            lgf[j] = (4 * g + j < 10) ? accL[j] + blv[j] : -1e30f;

        // in-register log_softmax over o (cross-g via shfl; same r in each quad)
        float m = fmaxf(fmaxf(lgf[0], lgf[1]), fmaxf(lgf[2], lgf[3]));
        m = fmaxf(m, __shfl_xor(m, 16, 64));
        m = fmaxf(m, __shfl_xor(m, 32, 64));
        float s = expf(lgf[0] - m) + expf(lgf[1] - m)
                + expf(lgf[2] - m) + expf(lgf[3] - m);
        s += __shfl_xor(s, 16, 64);
        s += __shfl_xor(s, 32, 64);
        float z = m + logf(s);

        // wave w stores rows {2w, 2w+1}
        if ((r >> 1) == w) {
            float* ob = out + (rowbase + (size_t)t * ROWST + r) * N_OUTS + 4 * g;
            if (g < 3) *(float2*)(ob)     = make_float2(lgf[0] - z, lgf[1] - z);
            if (g < 2) *(float2*)(ob + 2) = make_float2(lgf[2] - z, lgf[3] - z);
        }
    }
#undef STAGE
}

extern "C" void kernel_launch(void* const* d_in, const int* in_sizes, int n_in,
                              void* d_out, int out_size, void* d_ws, size_t ws_size,
                              hipStream_t stream) {
    const float* x      = (const float*)d_in[0];
    const float* W_in   = (const float*)d_in[1];
    const float* b_in   = (const float*)d_in[2];
    const float* W_gate = (const float*)d_in[3];
    const float* b_gate = (const float*)d_in[4];
    const float* W_data = (const float*)d_in[5];
    const float* b_data = (const float*)d_in[6];
    const float* W_out  = (const float*)d_in[7];
    const float* b_out  = (const float*)d_in[8];
    float* out = (float*)d_out;
    float* ws  = (float*)d_ws;

    prep1_kernel<<<1, 1024, 0, stream>>>(x, W_in, b_in, W_gate, b_gate,
                                         b_data, W_out, b_out, out, ws);
    prep2_kernel<<<256, 256, 0, stream>>>(W_in, W_data, ws);
    main_kernel<<<256, 512, 0, stream>>>(x, b_in, ws, out);
}